// Round 4
// baseline (372.880 us; speedup 1.0000x reference)
//
#include <hip/hip_runtime.h>

// GridInterpolator: trilinear interpolation over 8 voxel grids.
// vox: [8, 96, 96, 96, 16] f32, gidx: [N,1] i32, pts: [N,3] f32 -> out: [N,16] f32
//
// Two-phase: (1) bucket points by (grid, x/16, y/16, z/32) spatial slab so the
// gather stream is spatially local (L2/L3 reuse + DRAM row locality);
// (2) dense float4 gather, 4 threads/point, 8 dwordx4 loads per thread.

#define GDIM   96
#define NFEAT  16
#define NGRIDS 8
#define SBX 6
#define SBY 6
#define SBZ 3
#define NBUCK (NGRIDS * SBX * SBY * SBZ)   // 864
#define CAP 2048                           // mean fill ~1157, 26-sigma headroom

__device__ __forceinline__ int clampi(int v, int lo, int hi) {
    return v < lo ? lo : (v > hi ? hi : v);
}

// ---------------- zero bucket counters ----------------
__global__ void zero_cnt_kernel(int* __restrict__ cnt) {
    const int i = blockIdx.x * blockDim.x + threadIdx.x;
    if (i < NBUCK) cnt[i] = 0;
}

// ---------------- phase 1: bucket points ----------------
__global__ __launch_bounds__(256) void bucket_kernel(
    const float* __restrict__ vox,
    const int*   __restrict__ gidx,
    const float* __restrict__ pts,
    float*       __restrict__ out,
    float4*      __restrict__ slots,
    int*         __restrict__ cnt,
    int n_pts)
{
    const int p = blockIdx.x * blockDim.x + threadIdx.x;
    if (p >= n_pts) return;

    const float px = pts[3 * p + 0];
    const float py = pts[3 * p + 1];
    const float pz = pts[3 * p + 2];
    int gi = gidx[p];
    gi = clampi(gi, 0, NGRIDS - 1);   // memory safety; inputs guarantee [0,8)

    const float ux = (px + 1.0f) * 0.5f;
    const float uy = (py + 1.0f) * 0.5f;
    const float uz = (pz + 1.0f) * 0.5f;
    const int bx = clampi((int)(ux * (float)(GDIM - 1)), 0, GDIM - 1);
    const int by = clampi((int)(uy * (float)(GDIM - 1)), 0, GDIM - 1);
    const int bz = clampi((int)(uz * (float)(GDIM - 1)), 0, GDIM - 1);

    const int key = ((gi * SBX + (bx >> 4)) * SBY + (by >> 4)) * SBZ + (bz >> 5);
    const int pos = atomicAdd(&cnt[key], 1);

    if (pos < CAP) {
        float4 s;
        s.x = px; s.y = py; s.z = pz; s.w = __int_as_float(p);
        slots[key * CAP + pos] = s;
    } else {
        // overflow fallback (never hit with CAP=2048): compute inline, scalar
        const float sx = ux * (float)(GDIM - 1);
        const float sy = uy * (float)(GDIM - 1);
        const float sz = uz * (float)(GDIM - 1);
        const int ibx = (int)sx, iby = (int)sy, ibz = (int)sz;
        const float fx = sx - (float)ibx, fy = sy - (float)iby, fz = sz - (float)ibz;
        const bool inside = (ux >= 0.f) & (ux <= 1.f) & (uy >= 0.f) & (uy <= 1.f) &
                            (uz >= 0.f) & (uz <= 1.f);
        for (int f = 0; f < NFEAT; ++f) {
            float acc = 0.f;
            for (int k = 0; k < 8; ++k) {
                const int ox = k & 1, oy = (k >> 1) & 1, oz = (k >> 2) & 1;
                const int cx = clampi(ibx + ox, 0, GDIM - 1);
                const int cy = clampi(iby + oy, 0, GDIM - 1);
                const int cz = clampi(ibz + oz, 0, GDIM - 1);
                const float w = (ox ? fx : 1.f - fx) * (oy ? fy : 1.f - fy) * (oz ? fz : 1.f - fz);
                acc = fmaf(vox[(((gi * GDIM + cx) * GDIM + cy) * GDIM + cz) * NFEAT + f], w, acc);
            }
            out[p * NFEAT + f] = inside ? acc : 0.f;
        }
    }
}

// ---------------- phase 2: dense vectorized gather ----------------
__global__ __launch_bounds__(256) void gather_kernel(
    const float*  __restrict__ vox,
    const float4* __restrict__ slots,
    const int*    __restrict__ cnt,
    float*        __restrict__ out)
{
    const int bucket = blockIdx.x >> 2;       // 4 blocks per bucket
    const int q      = blockIdx.x & 3;
    int cb = cnt[bucket];
    cb = cb > CAP ? CAP : cb;
    const int lo = (cb * q) >> 2;
    const int hi = (cb * (q + 1)) >> 2;

    const int gi = bucket / (SBX * SBY * SBZ);
    const int f4 = (threadIdx.x & 3) << 2;    // feature base: 0,4,8,12
    const float4* __restrict__ base = slots + (size_t)bucket * CAP;

    for (int s = lo + (int)(threadIdx.x >> 2); s < hi; s += 64) {
        const float4 sd = base[s];
        const int p = __float_as_int(sd.w);

        const float ux = (sd.x + 1.0f) * 0.5f;
        const float uy = (sd.y + 1.0f) * 0.5f;
        const float uz = (sd.z + 1.0f) * 0.5f;
        const bool inside = (ux >= 0.f) & (ux <= 1.f) & (uy >= 0.f) & (uy <= 1.f) &
                            (uz >= 0.f) & (uz <= 1.f);

        const float sx = ux * (float)(GDIM - 1);
        const float sy = uy * (float)(GDIM - 1);
        const float sz = uz * (float)(GDIM - 1);
        const int bx = (int)sx, by = (int)sy, bz = (int)sz;
        const float fx = sx - (float)bx;
        const float fy = sy - (float)by;
        const float fz = sz - (float)bz;

        float ax = 0.f, ay = 0.f, az = 0.f, aw = 0.f;
#pragma unroll
        for (int k = 0; k < 8; ++k) {
            const int ox = k & 1, oy = (k >> 1) & 1, oz = (k >> 2) & 1;
            const int cx = clampi(bx + ox, 0, GDIM - 1);
            const int cy = clampi(by + oy, 0, GDIM - 1);
            const int cz = clampi(bz + oz, 0, GDIM - 1);
            const float4 v = *(const float4*)&vox[(size_t)((((gi * GDIM + cx) * GDIM + cy) * GDIM + cz) * NFEAT + f4)];
            const float w = (ox ? fx : 1.f - fx) * (oy ? fy : 1.f - fy) * (oz ? fz : 1.f - fz);
            ax = fmaf(v.x, w, ax);
            ay = fmaf(v.y, w, ay);
            az = fmaf(v.z, w, az);
            aw = fmaf(v.w, w, aw);
        }

        float4 r;
        r.x = inside ? ax : 0.f;
        r.y = inside ? ay : 0.f;
        r.z = inside ? az : 0.f;
        r.w = inside ? aw : 0.f;
        *(float4*)&out[(size_t)p * NFEAT + f4] = r;
    }
}

// ---------------- fallback: round-1 dense kernel ----------------
__global__ __launch_bounds__(256) void grid_interp_dense(
    const float* __restrict__ vox,
    const int*   __restrict__ gidx,
    const float* __restrict__ pts,
    float*       __restrict__ out,
    int n_total)
{
    const int stride = gridDim.x * blockDim.x;
    for (int tid = blockIdx.x * blockDim.x + threadIdx.x; tid < n_total; tid += stride) {
        const int p = tid >> 4;
        const int f = tid & 15;
        const float px = pts[p * 3 + 0];
        const float py = pts[p * 3 + 1];
        const float pz = pts[p * 3 + 2];
        const int gi = gidx[p];
        const float ux = (px + 1.0f) * 0.5f;
        const float uy = (py + 1.0f) * 0.5f;
        const float uz = (pz + 1.0f) * 0.5f;
        const bool inside = (ux >= 0.f) & (ux <= 1.f) & (uy >= 0.f) & (uy <= 1.f) &
                            (uz >= 0.f) & (uz <= 1.f);
        const float sx = ux * (float)(GDIM - 1);
        const float sy = uy * (float)(GDIM - 1);
        const float sz = uz * (float)(GDIM - 1);
        const int bx = (int)sx, by = (int)sy, bz = (int)sz;
        const float fx = sx - (float)bx, fy = sy - (float)by, fz = sz - (float)bz;
        const int gbase = gi * (GDIM * GDIM * GDIM);
        float acc = 0.0f;
#pragma unroll
        for (int k = 0; k < 8; ++k) {
            const int ox = k & 1, oy = (k >> 1) & 1, oz = (k >> 2) & 1;
            const int cx = clampi(bx + ox, 0, GDIM - 1);
            const int cy = clampi(by + oy, 0, GDIM - 1);
            const int cz = clampi(bz + oz, 0, GDIM - 1);
            const float w = (ox ? fx : 1.f - fx) * (oy ? fy : 1.f - fy) * (oz ? fz : 1.f - fz);
            acc = fmaf(vox[((gbase + cx * GDIM * GDIM + cy * GDIM + cz) << 4) + f], w, acc);
        }
        out[tid] = inside ? acc : 0.0f;
    }
}

extern "C" void kernel_launch(void* const* d_in, const int* in_sizes, int n_in,
                              void* d_out, int out_size, void* d_ws, size_t ws_size,
                              hipStream_t stream) {
    const float* vox  = (const float*)d_in[0];
    const int*   gidx = (const int*)  d_in[1];
    const float* pts  = (const float*)d_in[2];
    float*       outp = (float*)d_out;

    const int n_pts = in_sizes[1];

    // ws layout: cnt[NBUCK] at offset 0 (4096-B reserved), slots after
    const size_t slots_off = 4096;
    const size_t needed = slots_off + (size_t)NBUCK * CAP * sizeof(float4);

    if (ws_size < needed) {
        // not enough scratch: proven dense kernel
        grid_interp_dense<<<8192, 256, 0, stream>>>(vox, gidx, pts, outp, n_pts * NFEAT);
        return;
    }

    int*    cnt   = (int*)d_ws;
    float4* slots = (float4*)((char*)d_ws + slots_off);

    zero_cnt_kernel<<<(NBUCK + 255) / 256, 256, 0, stream>>>(cnt);
    bucket_kernel<<<(n_pts + 255) / 256, 256, 0, stream>>>(vox, gidx, pts, outp, slots, cnt, n_pts);
    gather_kernel<<<NBUCK * 4, 256, 0, stream>>>(vox, slots, cnt, outp);
}

// Round 6
// 133.229 us; speedup vs baseline: 2.7988x; 2.7988x over previous
//
#include <hip/hip_runtime.h>

// GridInterpolator: trilinear interpolation over 8 voxel grids.
// vox: [8, 96, 96, 96, 16] f32, gidx: [N,1] i32, pts: [N,3] f32 -> out: [N,16] f32
//
// Dense one-pass gather. 4 threads per point (one per feature-quad); each
// thread issues 8 float4 (dwordx4) corner loads. The 4 lanes of a point
// together read each corner's full 64-B cell -> one coalesced segment.
// out/pts/gidx are single-use streams: nontemporal so L2/L3 stay dedicated
// to the 432-MiB voxel table (12M line-touches on ~3.4M unique lines).

#define GDIM  96
#define NFEAT 16

typedef float f32x4 __attribute__((ext_vector_type(4)));

__device__ __forceinline__ int clampi(int v, int lo, int hi) {
    return v < lo ? lo : (v > hi ? hi : v);
}

__global__ __launch_bounds__(256) void grid_interp_v4(
    const f32x4* __restrict__ vox4,   // [8*96*96*96*4] float4
    const int*   __restrict__ gidx,
    const float* __restrict__ pts,
    f32x4*       __restrict__ out4,   // [N*4] float4
    int n_tasks)                       // N * 4
{
    const int tid = blockIdx.x * blockDim.x + threadIdx.x;
    if (tid >= n_tasks) return;

    const int p  = tid >> 2;   // point index
    const int fq = tid & 3;    // feature quad 0..3

    // 4 lanes of a point read the same addresses -> broadcast
    const float px = __builtin_nontemporal_load(&pts[p * 3 + 0]);
    const float py = __builtin_nontemporal_load(&pts[p * 3 + 1]);
    const float pz = __builtin_nontemporal_load(&pts[p * 3 + 2]);
    const int   gi = __builtin_nontemporal_load(&gidx[p]);

    // remap [-1,1] -> [0,1]
    const float ux = (px + 1.0f) * 0.5f;
    const float uy = (py + 1.0f) * 0.5f;
    const float uz = (pz + 1.0f) * 0.5f;
    const bool inside = (ux >= 0.0f) & (ux <= 1.0f) &
                        (uy >= 0.0f) & (uy <= 1.0f) &
                        (uz >= 0.0f) & (uz <= 1.0f);

    const float sx = ux * (float)(GDIM - 1);
    const float sy = uy * (float)(GDIM - 1);
    const float sz = uz * (float)(GDIM - 1);
    const int bx = (int)sx, by = (int)sy, bz = (int)sz;
    const float fx = sx - (float)bx;
    const float fy = sy - (float)by;
    const float fz = sz - (float)bz;

    const int gbase = gi * (GDIM * GDIM * GDIM);

    float ax = 0.f, ay = 0.f, az = 0.f, aw = 0.f;
#pragma unroll
    for (int k = 0; k < 8; ++k) {
        const int ox = k & 1, oy = (k >> 1) & 1, oz = (k >> 2) & 1;
        const int cx = clampi(bx + ox, 0, GDIM - 1);
        const int cy = clampi(by + oy, 0, GDIM - 1);
        const int cz = clampi(bz + oz, 0, GDIM - 1);
        const int cell = gbase + cx * (GDIM * GDIM) + cy * GDIM + cz;
        const f32x4 v = vox4[(size_t)(cell << 2) + fq];
        const float w = (ox ? fx : 1.0f - fx) *
                        (oy ? fy : 1.0f - fy) *
                        (oz ? fz : 1.0f - fz);
        ax = fmaf(v.x, w, ax);
        ay = fmaf(v.y, w, ay);
        az = fmaf(v.z, w, az);
        aw = fmaf(v.w, w, aw);
    }

    f32x4 r;
    r.x = inside ? ax : 0.f;
    r.y = inside ? ay : 0.f;
    r.z = inside ? az : 0.f;
    r.w = inside ? aw : 0.f;
    __builtin_nontemporal_store(r, &out4[tid]);
}

extern "C" void kernel_launch(void* const* d_in, const int* in_sizes, int n_in,
                              void* d_out, int out_size, void* d_ws, size_t ws_size,
                              hipStream_t stream) {
    const f32x4* vox4 = (const f32x4*)d_in[0];
    const int*   gidx = (const int*)  d_in[1];
    const float* pts  = (const float*)d_in[2];
    f32x4*       out4 = (f32x4*)d_out;

    const int n_pts   = in_sizes[1];   // N
    const int n_tasks = n_pts * 4;     // N * 4 feature-quads

    const int threads = 256;
    const int blocks  = (n_tasks + threads - 1) / threads;   // 16384 at N=1M

    grid_interp_v4<<<blocks, threads, 0, stream>>>(vox4, gidx, pts, out4, n_tasks);
}